// Round 8
// baseline (331.032 us; speedup 1.0000x reference)
//
#include <hip/hip_runtime.h>
#include <hip/hip_cooperative_groups.h>
#include <math.h>

namespace cg = cooperative_groups;

typedef _Float16 f16;
typedef _Float16 f16x8 __attribute__((ext_vector_type(8)));
typedef _Float16 f16x4 __attribute__((ext_vector_type(4)));
typedef float    f32x4 __attribute__((ext_vector_type(4)));

#define BATCH 32
#define TT    600
#define CC    64
#define SEG   50
#define HH    512
#define G4    2048
#define FF    2144   // IN_SIZE = 64 + 2080
#define MM    1600   // BATCH*SEG
#define MP    1664   // padded: 52*32 (s-major) = 26*64 M-tiles
#define NPAIR 2016   // C*(C-1)/2
#define WRK   208    // worker blocks: prep phase then 2 gemm tiles each

struct TV { int v[51]; };

// async global->LDS, 16B per lane. LDS dest must be wave-uniform base + lane*16.
__device__ __forceinline__ void async_copy16(char* lds, const char* g) {
  __builtin_amdgcn_global_load_lds(
      (const __attribute__((address_space(1))) unsigned int*)g,
      (__attribute__((address_space(3))) unsigned int*)lds, 16, 0, 0);
}

__device__ __forceinline__ float sigm(float x) { return 1.f / (1.f + __expf(-x)); }
__device__ __forceinline__ float tanh_(float x) {
  float ax = fabsf(x);
  float e  = __expf(2.f * ax);
  float t  = 1.f - 2.f / (e + 1.f);   // robust for large |x|
  return x < 0.f ? -t : t;
}
__device__ __forceinline__ unsigned short f16_bits(f16 v) {
  union { f16 f; unsigned short u; } c; c.f = v; return c.u;
}
__device__ __forceinline__ unsigned int f32_bits(float v) {
  union { float f; unsigned int u; } c; c.f = v; return c.u;
}
__device__ __forceinline__ float bits_f32(unsigned int v) {
  union { unsigned int u; float f; } c; c.u = v; return c.f;
}
// sc1 (agent-scope, write-through to coherence point) helpers
__device__ __forceinline__ void st16(unsigned short* p, unsigned short v) {
  __hip_atomic_store(p, v, __ATOMIC_RELAXED, __HIP_MEMORY_SCOPE_AGENT);
}
__device__ __forceinline__ void st32(unsigned int* p, unsigned int v) {
  __hip_atomic_store(p, v, __ATOMIC_RELAXED, __HIP_MEMORY_SCOPE_AGENT);
}
__device__ __forceinline__ void st64(unsigned long long* p, unsigned long long v) {
  __hip_atomic_store(p, v, __ATOMIC_RELAXED, __HIP_MEMORY_SCOPE_AGENT);
}

// ================= single cooperative kernel: prep + GEMM + LSTM =================
// Blocks 32..239 (workers): phase1 = w16 convert + feats (sc1 stores) -> flag
//   barrier among workers -> phase2 = 2 GEMM tiles (M-major), sc1 gx + tile flag.
// Blocks 0..31 (lstm): build w_hh fragments from fp32 input (no dependency),
//   then R6 flag-protocol recurrence, gated per M-tile on gxrdy.
// All flags are sign-checked ints: 0xAAAAAAAA ws-poison is negative -> no init pass.
__global__ __launch_bounds__(256) void fused_kernel(
    const float* __restrict__ x, TV tv,
    const float4* __restrict__ w_ih, const float* __restrict__ w_hh,
    const float* __restrict__ bih, const float* __restrict__ bhh,
    f16* __restrict__ fhi, f16* __restrict__ w16, float* __restrict__ gx,
    unsigned short* __restrict__ hbuf, unsigned int* __restrict__ ready,
    int* __restrict__ gxrdy, int* __restrict__ prepflag,
    float* __restrict__ out) {
  __shared__ __align__(16) char smem[40960];
  int tid  = threadIdx.x;
  int lane = tid & 63;

  if (blockIdx.x >= 32) {
    // ================= WORKER role =================
    int w = blockIdx.x - 32;

    // ---- phase 1a: convert w_ih -> w16 (sc1) ----
    {
      unsigned long long* w16q = (unsigned long long*)w16;
      int gtid = w * 256 + tid;
      int nth  = WRK * 256;
      for (int i = gtid; i < G4 * FF / 4; i += nth) {
        float4 v = w_ih[i];
        union { f16x4 h; unsigned long long u; } pk;
        pk.h = (f16x4){(f16)v.x, (f16)v.y, (f16)v.z, (f16)v.w};
        st64(w16q + i, pk.u);
      }
    }

    // ---- phase 1b: feats rows w*8 .. w*8+7 (sc1) ----
    {
      float* xs = (float*)smem;   // 13*64 floats
      for (int rr = 0; rr < 8; rr++) {
        int m = w * 8 + rr;
        unsigned short* rhi = (unsigned short*)(fhi + (size_t)m * FF);
        if (m >= MM) {            // zero-pad rows 1600..1663
          unsigned int* a = (unsigned int*)rhi;
          for (int i = tid; i < FF / 2; i += 256) st32(a + i, 0u);
          continue;
        }
        int bb = m & 31, ss = m >> 5;
        int t0 = tv.v[ss] - 1, t1 = tv.v[ss + 1] - 1;
        int len = t1 - t0;        // 11..12
        for (int i = tid; i < (len + 1) * CC; i += 256)
          xs[i] = x[(size_t)bb * TT * CC + (size_t)(t0 + (i >> 6)) * CC + (i & 63)];
        __syncthreads();

        if (tid < CC) {           // inc (cols 0..63) and xa (cols 2080..2143)
          float xa  = xs[tid];
          float inc = xs[len * CC + tid] - xa;
          st16(rhi + tid, f16_bits((f16)inc));
          st16(rhi + 2080 + tid, f16_bits((f16)xa));
        }
        int p0 = tid * 8;
        if (p0 < NPAIR) {
          int c = 0, rem = p0;
          while (rem >= 63 - c) { rem -= 63 - c; c++; }
          int d = c + 1 + rem;
          int cs[8], dd[8];
#pragma unroll
          for (int i = 0; i < 8; i++) {
            cs[i] = c; dd[i] = d;
            d++; if (d == 64) { c++; d = c + 1; }
          }
          float acc[8], xc[8], xd[8];
#pragma unroll
          for (int i = 0; i < 8; i++) { acc[i] = 0.f; xc[i] = xs[cs[i]]; xd[i] = xs[dd[i]]; }
          for (int t = 1; t <= len; t++) {
#pragma unroll
            for (int i = 0; i < 8; i++) {   // Levy area
              float nc = xs[t * CC + cs[i]], nd = xs[t * CC + dd[i]];
              acc[i] += xc[i] * (nd - xd[i]) - xd[i] * (nc - xc[i]);
              xc[i] = nc; xd[i] = nd;
            }
          }
#pragma unroll
          for (int i = 0; i < 8; i++) {
            int ci = cs[i], di = dd[i];
            float xac = xs[ci], xad = xs[di];
            float incc = xs[len * CC + ci] - xac, incd = xs[len * CC + di] - xad;
            float v = 0.5f * acc[i] - 0.5f * (xac * incd - xad * incc);
            st16(rhi + 64 + p0 + i, f16_bits((f16)v));
          }
        }
        __syncthreads();          // xs reused next row
      }
    }

    // ---- worker barrier: my sc1 stores acked, then wait for all workers ----
    __syncthreads();              // drains vmcnt(0): phase-1 stores at coherence pt
    if (tid == 0)
      __hip_atomic_store(&prepflag[w], 1, __ATOMIC_RELAXED, __HIP_MEMORY_SCOPE_AGENT);
    if (tid < WRK) {
      while (__hip_atomic_load(&prepflag[tid], __ATOMIC_RELAXED,
                               __HIP_MEMORY_SCOPE_AGENT) <= 0)
        __builtin_amdgcn_s_sleep(1);
    }
    __syncthreads();

    // ---- phase 2: GEMM, tiles id = w, w+WRK (M-major: mt=id>>4, nt=id&15) ----
    int wn = tid >> 6;
    char* ldsA = smem;
    char* ldsB = smem + 4096;
    int rowq = tid >> 2;
    int colq = (tid & 3) * 8;
    int ldst = tid * 16;
    int quad16 = (lane >> 4) * 16;
    int am = lane & 15;
    unsigned int* gxa = (unsigned int*)gx;

    for (int t = 0; t < 2; t++) {
      int id = w + t * WRK;
      int mt = id >> 4, nt = id & 15;
      int m0 = mt * 64, n0 = nt * 128;

      const f16* pa  = fhi + (size_t)(m0 + rowq) * FF + colq;
      const f16* pb0 = w16 + (size_t)(n0 + rowq) * FF + colq;
      const f16* pb1 = pb0 + (size_t)64 * FF;

      f32x4 zero4 = {0.f, 0.f, 0.f, 0.f};
      f32x4 acc[4][2];
#pragma unroll
      for (int i = 0; i < 4; i++) { acc[i][0] = zero4; acc[i][1] = zero4; }

      for (int kt = 0; kt < FF / 32; kt++) {
        int koff = kt * 32;
        async_copy16(ldsA + ldst,        (const char*)(pa + koff));
        async_copy16(ldsB + ldst,        (const char*)(pb0 + koff));
        async_copy16(ldsB + 4096 + ldst, (const char*)(pb1 + koff));
        __syncthreads();

        f16x8 bfr[2];
#pragma unroll
        for (int ni = 0; ni < 2; ni++)
          bfr[ni] = *(const f16x8*)(ldsB + (wn * 32 + ni * 16 + am) * 64 + quad16);
#pragma unroll
        for (int mi = 0; mi < 4; mi++) {
          f16x8 ah = *(const f16x8*)(ldsA + (mi * 16 + am) * 64 + quad16);
#pragma unroll
          for (int ni = 0; ni < 2; ni++)
            acc[mi][ni] = __builtin_amdgcn_mfma_f32_16x16x32_f16(ah, bfr[ni], acc[mi][ni], 0, 0, 0);
        }
        __syncthreads();
      }

#pragma unroll
      for (int ni = 0; ni < 2; ni++) {
        int ncol = n0 + wn * 32 + ni * 16 + (lane & 15);
        float bv = bih[ncol] + bhh[ncol];
#pragma unroll
        for (int mi = 0; mi < 4; mi++) {
          int mrow = m0 + mi * 16 + (lane >> 4) * 4;
#pragma unroll
          for (int r = 0; r < 4; r++)
            st32(gxa + (size_t)(mrow + r) * G4 + ncol, f32_bits(acc[mi][ni][r] + bv));
        }
      }
      __syncthreads();            // drains vmcnt(0): tile's gx stores acked
      if (tid == 0)
        __hip_atomic_store(&gxrdy[id], 1, __ATOMIC_RELAXED, __HIP_MEMORY_SCOPE_AGENT);
    }
    return;
  }

  // ================= LSTM role (blocks 0..31) =================
  f16* hs = (f16*)smem;                 // 32 KB, layout [k8][b][8] fp16
  float* gb = (float*)(smem + 32768);   // 8 KB gate exchange [gate][b][16]

  int gate = tid >> 6;
  int u0   = blockIdx.x * 16;
  int wg   = blockIdx.x;

  // w_hh fragments straight from fp32 input (no worker dependency)
  f16x8 bf[16];
  {
    const float* wrow = w_hh + (size_t)(gate * HH + u0 + (lane & 15)) * HH + (lane >> 4) * 8;
#pragma unroll
    for (int ks = 0; ks < 16; ks++) {
      float4 a = *(const float4*)(wrow + ks * 32);
      float4 b = *(const float4*)(wrow + ks * 32 + 4);
      bf[ks] = (f16x8){(f16)a.x, (f16)a.y, (f16)a.z, (f16)a.w,
                       (f16)b.x, (f16)b.y, (f16)b.z, (f16)b.w};
    }
  }

  int b1 = tid >> 4;
  int ul = tid & 15;
  float cst0 = 0.f, cst1 = 0.f;
  int aq  = (lane >> 4);
  int am  = (lane & 15);
  int col = lane & 15;
  int rbase = (lane >> 4) * 4;
  const unsigned int* gxa = (const unsigned int*)gx;

  for (int s = 0; s < SEG; s++) {
    // gate on gx M-tile (s>>1); odd s confirmed at s-1. Sign-checked flags.
    if ((s & 1) == 0) {
      if (tid < 16) {
        const int* rp = &gxrdy[(s >> 1) * 16 + tid];
        while (__hip_atomic_load(rp, __ATOMIC_RELAXED,
                                 __HIP_MEMORY_SCOPE_AGENT) <= 0)
          __builtin_amdgcn_s_sleep(1);
      }
      __syncthreads();
    }

    // gx loads (sc1; in flight across the h-ready poll)
    float gxr0[4], gxr1[4];
#pragma unroll
    for (int r = 0; r < 4; r++) {
      int b = rbase + r;
      gxr0[r] = bits_f32(__hip_atomic_load(
          gxa + (size_t)((s << 5) + b) * G4 + gate * HH + u0 + col,
          __ATOMIC_RELAXED, __HIP_MEMORY_SCOPE_AGENT));
      gxr1[r] = bits_f32(__hip_atomic_load(
          gxa + (size_t)((s << 5) + b + 16) * G4 + gate * HH + u0 + col,
          __ATOMIC_RELAXED, __HIP_MEMORY_SCOPE_AGENT));
    }

    f32x4 acc0 = {0.f, 0.f, 0.f, 0.f};
    f32x4 acc1 = {0.f, 0.f, 0.f, 0.f};

    if (s > 0) {
      // wait: all 32 WGs published h[s] (ready values 1..49 positive; poison neg)
      int tgt = s;
      if (tid < 32) {
        while (__hip_atomic_load((const int*)&ready[tid * 16], __ATOMIC_RELAXED,
                                 __HIP_MEMORY_SCOPE_AGENT) < tgt)
          __builtin_amdgcn_s_sleep(1);
      }
      __syncthreads();

      // stage h[s] -> LDS: 16 u64 coherent loads
      const unsigned long long* hrd =
          (const unsigned long long*)(hbuf + (size_t)(s & 1) * (BATCH * HH));
      unsigned long long v[16];
#pragma unroll
      for (int i = 0; i < 16; i++)
        v[i] = __hip_atomic_load(hrd + i * 256 + tid, __ATOMIC_RELAXED,
                                 __HIP_MEMORY_SCOPE_AGENT);
      unsigned long long* hw = (unsigned long long*)hs;
#pragma unroll
      for (int i = 0; i < 16; i++) hw[i * 256 + tid] = v[i];
      __syncthreads();

#pragma unroll
      for (int ks = 0; ks < 16; ks++) {
        f16x8 a0 = *(const f16x8*)((char*)hs + (((ks * 4 + aq) * 32) + am) * 16);
        f16x8 a1 = *(const f16x8*)((char*)hs + (((ks * 4 + aq) * 32) + 16 + am) * 16);
        acc0 = __builtin_amdgcn_mfma_f32_16x16x32_f16(a0, bf[ks], acc0, 0, 0, 0);
        acc1 = __builtin_amdgcn_mfma_f32_16x16x32_f16(a1, bf[ks], acc1, 0, 0, 0);
      }
    }

#pragma unroll
    for (int r = 0; r < 4; r++) {
      int b = rbase + r;
      gb[(gate * 32 + b) * 16 + col]      = acc0[r] + gxr0[r];
      gb[(gate * 32 + b + 16) * 16 + col] = acc1[r] + gxr1[r];
    }
    __syncthreads();

    unsigned short* hwr = hbuf + (size_t)((s + 1) & 1) * (BATCH * HH);
    int k = u0 + ul;
    float h0, h1;
    {
      float i_ = sigm(gb[(0 * 32 + b1) * 16 + ul]), f_ = sigm(gb[(1 * 32 + b1) * 16 + ul]);
      float g_ = tanh_(gb[(2 * 32 + b1) * 16 + ul]), o_ = sigm(gb[(3 * 32 + b1) * 16 + ul]);
      cst0 = f_ * cst0 + i_ * g_;
      h0 = o_ * tanh_(cst0);
      out[(size_t)(b1 * SEG + s) * HH + k] = h0;
    }
    {
      int b2 = b1 + 16;
      float i_ = sigm(gb[(0 * 32 + b2) * 16 + ul]), f_ = sigm(gb[(1 * 32 + b2) * 16 + ul]);
      float g_ = tanh_(gb[(2 * 32 + b2) * 16 + ul]), o_ = sigm(gb[(3 * 32 + b2) * 16 + ul]);
      cst1 = f_ * cst1 + i_ * g_;
      h1 = o_ * tanh_(cst1);
      out[(size_t)(b2 * SEG + s) * HH + k] = h1;
    }

    if (s < SEG - 1) {
      // publish h[s+1]; __syncthreads drains vmcnt(0) before the flag goes out
      st16(hwr + ((k >> 3) * 32 + b1) * 8 + (k & 7), f16_bits((f16)h0));
      st16(hwr + ((k >> 3) * 32 + (b1 + 16)) * 8 + (k & 7), f16_bits((f16)h1));
      __syncthreads();
      if (tid == 0)
        __hip_atomic_store((int*)&ready[wg * 16], s + 1,
                           __ATOMIC_RELAXED, __HIP_MEMORY_SCOPE_AGENT);
    }
  }
}

// ---------------- launch ----------------
extern "C" void kernel_launch(void* const* d_in, const int* in_sizes, int n_in,
                              void* d_out, int out_size, void* d_ws, size_t ws_size,
                              hipStream_t stream) {
  const float* x    = (const float*)d_in[0];
  const float* w_ih = (const float*)d_in[1];
  const float* w_hh = (const float*)d_in[2];
  const float* b_ih = (const float*)d_in[3];
  const float* b_hh = (const float*)d_in[4];
  float* out = (float*)d_out;

  char* ws = (char*)d_ws;
  f16*   fhi  = (f16*)(ws + 0);              // 1664*2144*2 = 7,135,232
  f16*   w16  = (f16*)(ws + 7135232);        // 2048*2144*2 = 8,785,920
  float* gx   = (float*)(ws + 15921152);     // 1664*2048*4 = 13,631,488
  unsigned short* hbuf  = (unsigned short*)(ws + 29552640); // 2*32KB ping-pong
  unsigned int*   ready = (unsigned int*)(ws + 29618176);   // 32 slots x 64B
  int*            gxrdy = (int*)(ws + 29620224);            // 416 tile flags
  int*            pflag = (int*)(ws + 29621888);            // 208 worker flags

  // bit-exact replication of np.linspace(1,600,51) + Python round (half-even)
  TV tv;
  double step = 599.0 / 50.0;
  for (int i = 0; i <= 50; i++) {
    double v = (double)i * step + 1.0;
    tv.v[i] = (int)nearbyint(v);
  }
  tv.v[50] = 600;

  void* args[] = { (void*)&x, (void*)&tv, (void*)&w_ih, (void*)&w_hh,
                   (void*)&b_ih, (void*)&b_hh, (void*)&fhi, (void*)&w16,
                   (void*)&gx, (void*)&hbuf, (void*)&ready, (void*)&gxrdy,
                   (void*)&pflag, (void*)&out };
  hipLaunchCooperativeKernel((void*)fused_kernel, dim3(32 + WRK), dim3(256), args, 0, stream);
}

// Round 9
// 270.027 us; speedup vs baseline: 1.2259x; 1.2259x over previous
//
#include <hip/hip_runtime.h>
#include <math.h>

typedef _Float16 f16;
typedef _Float16 f16x8 __attribute__((ext_vector_type(8)));
typedef _Float16 f16x4 __attribute__((ext_vector_type(4)));
typedef float    f32x4 __attribute__((ext_vector_type(4)));

#define BATCH 32
#define TT    600
#define CC    64
#define SEG   50
#define HH    512
#define G4    2048
#define FF    2144   // IN_SIZE = 64 + 2080
#define MM    1600   // BATCH*SEG
#define MP    1664   // padded: 52*32 (s-major) = 26*64 M-tiles
#define NPAIR 2016   // C*(C-1)/2
#define CVB   512    // convert blocks appended to prep grid
#define WRK   208    // gemm worker blocks (each does exactly 2 of the 416 tiles)

struct TV { int v[51]; };

// async global->LDS, 16B per lane. LDS dest must be wave-uniform base + lane*16.
__device__ __forceinline__ void async_copy16(char* lds, const char* g) {
  __builtin_amdgcn_global_load_lds(
      (const __attribute__((address_space(1))) unsigned int*)g,
      (__attribute__((address_space(3))) unsigned int*)lds, 16, 0, 0);
}

__device__ __forceinline__ float sigm(float x) { return 1.f / (1.f + __expf(-x)); }
__device__ __forceinline__ float tanh_(float x) {
  float ax = fabsf(x);
  float e  = __expf(2.f * ax);
  float t  = 1.f - 2.f / (e + 1.f);   // robust for large |x|
  return x < 0.f ? -t : t;
}
__device__ __forceinline__ unsigned short f16_bits(f16 v) {
  union { f16 f; unsigned short u; } c; c.f = v; return c.u;
}
__device__ __forceinline__ unsigned int f32_bits(float v) {
  union { float f; unsigned int u; } c; c.f = v; return c.u;
}
__device__ __forceinline__ float bits_f32(unsigned int v) {
  union { unsigned int u; float f; } c; c.u = v; return c.f;
}

// ---------------- kernel 1: feats (blocks 0..MP-1) + weight convert (blocks MP..) ----
// Plain cached stores; stream order makes them visible to the fused kernel.
__global__ void prep_kernel(const float* __restrict__ x, f16* __restrict__ fhi, TV tv,
                            const float4* __restrict__ w_ih, const float4* __restrict__ w_hh,
                            f16x4* __restrict__ w16, f16x4* __restrict__ whh16,
                            unsigned int* __restrict__ ready) {
  __shared__ float xs[13 * CC];
  int m   = blockIdx.x;
  int tid = threadIdx.x;

  if (m >= MP) {              // ---- convert role ----
    int cb   = m - MP;
    int gtid = cb * 256 + tid;
    int nth  = CVB * 256;
    for (int i = gtid; i < G4 * FF / 4; i += nth) {
      float4 v = w_ih[i];
      f16x4 o = {(f16)v.x, (f16)v.y, (f16)v.z, (f16)v.w};
      w16[i] = o;
    }
    for (int i = gtid; i < G4 * HH / 4; i += nth) {
      float4 v = w_hh[i];
      f16x4 o = {(f16)v.x, (f16)v.y, (f16)v.z, (f16)v.w};
      whh16[i] = o;
    }
    if (cb == 0)               // zero 32 ready slots (512 u32) + 32 gx tile counters
      for (int i = tid; i < 544; i += 256) ready[i] = 0u;
    return;
  }

  f16* rhi = fhi + (size_t)m * FF;
  if (m >= MM) {              // zero-pad rows 1600..1663 (s = 50,51) for the GEMM M-edge
    unsigned int* a = (unsigned int*)rhi;
    for (int i = tid; i < FF / 2; i += 256) a[i] = 0u;
    return;
  }
  int bb = m & 31, ss = m >> 5;
  int t0 = tv.v[ss] - 1, t1 = tv.v[ss + 1] - 1;
  int len = t1 - t0;          // #intervals in segment (11..12)
  for (int i = tid; i < (len + 1) * CC; i += 256)
    xs[i] = x[(size_t)bb * TT * CC + (size_t)(t0 + (i >> 6)) * CC + (i & 63)];
  __syncthreads();

  if (tid < CC) {             // inc (cols 0..63) and xa (cols 2080..2143)
    float xa  = xs[tid];
    float inc = xs[len * CC + tid] - xa;
    rhi[tid] = (f16)inc;
    rhi[2080 + tid] = (f16)xa;
  }

  int p0 = tid * 8;           // 252 threads x 8 pairs = 2016 upper-tri pairs
  if (p0 < NPAIR) {
    int c = 0, rem = p0;
    while (rem >= 63 - c) { rem -= 63 - c; c++; }
    int d = c + 1 + rem;
    int cs[8], dd[8];
#pragma unroll
    for (int i = 0; i < 8; i++) {
      cs[i] = c; dd[i] = d;
      d++; if (d == 64) { c++; d = c + 1; }
    }
    float acc[8], xc[8], xd[8];
#pragma unroll
    for (int i = 0; i < 8; i++) { acc[i] = 0.f; xc[i] = xs[cs[i]]; xd[i] = xs[dd[i]]; }
    for (int t = 1; t <= len; t++) {
#pragma unroll
      for (int i = 0; i < 8; i++) {      // Levy area: sum x_c*dx_d - x_d*dx_c
        float nc = xs[t * CC + cs[i]], nd = xs[t * CC + dd[i]];
        acc[i] += xc[i] * (nd - xd[i]) - xd[i] * (nc - xc[i]);
        xc[i] = nc; xd[i] = nd;
      }
    }
#pragma unroll
    for (int i = 0; i < 8; i++) {
      int ci = cs[i], di = dd[i];
      float xac = xs[ci], xad = xs[di];
      float incc = xs[len * CC + ci] - xac, incd = xs[len * CC + di] - xad;
      float v = 0.5f * acc[i] - 0.5f * (xac * incd - xad * incc);
      rhi[64 + p0 + i] = (f16)v;
    }
  }
}

// ---------------- kernel 2: fused GEMM + LSTM, REGULAR launch (240 blocks <= 256 CUs
// -> all co-resident; no grid.sync needed, pure flag dataflow) ----
// Blocks 0..31: persistent LSTM (flag protocol), gated per-2-steps on gx tile flags.
// Blocks 32..239: GEMM workers, 2 tiles each, M-major order (tiles w, w+208).
// gx crosses block groups via sc1 (agent-scope) stores/loads + per-M-tile counters.
__global__ __launch_bounds__(256) void fused_kernel(
    const f16* __restrict__ fhi, const f16* __restrict__ w16,
    const float* __restrict__ bih, const float* __restrict__ bhh,
    const f16* __restrict__ whh16, float* __restrict__ gx,
    unsigned short* __restrict__ hbuf, unsigned int* __restrict__ ready,
    unsigned int* __restrict__ gxcnt, float* __restrict__ out) {
  __shared__ __align__(16) char smem[40960];  // lstm: hs 32K + gbuf 8K ; gemm: A 4K + B 8K
  int tid  = threadIdx.x;
  int lane = tid & 63;

  if (blockIdx.x >= 32) {
    // ================= GEMM worker role =================
    int w  = blockIdx.x - 32;
    int wn = tid >> 6;
    char* ldsA = smem;
    char* ldsB = smem + 4096;
    int rowq = tid >> 2;            // 0..63
    int colq = (tid & 3) * 8;       // halves
    int ldst = tid * 16;
    int quad16 = (lane >> 4) * 16;
    int am = lane & 15;
    unsigned int* gxa = (unsigned int*)gx;

    for (int t = 0; t < 2; t++) {
      int id = w + t * WRK;         // 0..415, M-major: mt = id/16, nt = id%16
      int mt = id >> 4, nt = id & 15;
      int m0 = mt * 64, n0 = nt * 128;

      const f16* pa  = fhi + (size_t)(m0 + rowq) * FF + colq;
      const f16* pb0 = w16 + (size_t)(n0 + rowq) * FF + colq;
      const f16* pb1 = pb0 + (size_t)64 * FF;

      f32x4 zero4 = {0.f, 0.f, 0.f, 0.f};
      f32x4 acc[4][2];
#pragma unroll
      for (int i = 0; i < 4; i++) { acc[i][0] = zero4; acc[i][1] = zero4; }

      for (int kt = 0; kt < FF / 32; kt++) {
        int koff = kt * 32;
        async_copy16(ldsA + ldst,        (const char*)(pa + koff));
        async_copy16(ldsB + ldst,        (const char*)(pb0 + koff));
        async_copy16(ldsB + 4096 + ldst, (const char*)(pb1 + koff));
        __syncthreads();

        f16x8 bfr[2];
#pragma unroll
        for (int ni = 0; ni < 2; ni++)
          bfr[ni] = *(const f16x8*)(ldsB + (wn * 32 + ni * 16 + am) * 64 + quad16);
#pragma unroll
        for (int mi = 0; mi < 4; mi++) {
          f16x8 ah = *(const f16x8*)(ldsA + (mi * 16 + am) * 64 + quad16);
#pragma unroll
          for (int ni = 0; ni < 2; ni++)
            acc[mi][ni] = __builtin_amdgcn_mfma_f32_16x16x32_f16(ah, bfr[ni], acc[mi][ni], 0, 0, 0);
        }
        __syncthreads();
      }

      // epilogue: sc1 stores so lstm blocks (other XCDs) see gx at the coherence point
#pragma unroll
      for (int ni = 0; ni < 2; ni++) {
        int ncol = n0 + wn * 32 + ni * 16 + (lane & 15);
        float bv = bih[ncol] + bhh[ncol];
#pragma unroll
        for (int mi = 0; mi < 4; mi++) {
          int mrow = m0 + mi * 16 + (lane >> 4) * 4;
#pragma unroll
          for (int r = 0; r < 4; r++)
            __hip_atomic_store(gxa + (size_t)(mrow + r) * G4 + ncol,
                               f32_bits(acc[mi][ni][r] + bv),
                               __ATOMIC_RELAXED, __HIP_MEMORY_SCOPE_AGENT);
        }
      }
      __syncthreads();   // drains vmcnt(0): all this block's gx stores acked
      if (tid == 0)
        __hip_atomic_fetch_add(&gxcnt[mt], 1u, __ATOMIC_RELAXED,
                               __HIP_MEMORY_SCOPE_AGENT);
    }
    return;
  }

  // ================= LSTM role (blocks 0..31) =================
  f16* hs = (f16*)smem;                         // 32 KB, layout [k8][b][8] fp16
  float* gb = (float*)(smem + 32768);           // 8 KB gate exchange [gate][b][16]

  int gate = tid >> 6;
  int u0   = blockIdx.x * 16;
  int wg   = blockIdx.x;

  // preload w_hh fragments: B[k][n] = w_hh[n][k], n = gate*512 + u0 + (lane&15)
  f16x8 bf[16];
  {
    const f16* wrow = whh16 + (size_t)(gate * HH + u0 + (lane & 15)) * HH + (lane >> 4) * 8;
#pragma unroll
    for (int ks = 0; ks < 16; ks++) bf[ks] = *(const f16x8*)(wrow + ks * 32);
  }

  int b1 = tid >> 4;
  int ul = tid & 15;
  float cst0 = 0.f, cst1 = 0.f;
  int aq  = (lane >> 4);
  int am  = (lane & 15);
  int col = lane & 15;
  int rbase = (lane >> 4) * 4;
  const unsigned int* gxa = (const unsigned int*)gx;

  for (int s = 0; s < SEG; s++) {
    // gate on gx tile (s>>1); odd s was confirmed at s-1
    if ((s & 1) == 0) {
      if (tid == 0) {
        while (__hip_atomic_load(&gxcnt[s >> 1], __ATOMIC_RELAXED,
                                 __HIP_MEMORY_SCOPE_AGENT) < 16u)
          __builtin_amdgcn_s_sleep(1);
      }
      __syncthreads();
    }

    // gx loads (sc1; in flight across the h-ready poll)
    float gxr0[4], gxr1[4];
#pragma unroll
    for (int r = 0; r < 4; r++) {
      int b = rbase + r;
      gxr0[r] = bits_f32(__hip_atomic_load(
          gxa + (size_t)((s << 5) + b) * G4 + gate * HH + u0 + col,
          __ATOMIC_RELAXED, __HIP_MEMORY_SCOPE_AGENT));
      gxr1[r] = bits_f32(__hip_atomic_load(
          gxa + (size_t)((s << 5) + b + 16) * G4 + gate * HH + u0 + col,
          __ATOMIC_RELAXED, __HIP_MEMORY_SCOPE_AGENT));
    }

    f32x4 acc0 = {0.f, 0.f, 0.f, 0.f};
    f32x4 acc1 = {0.f, 0.f, 0.f, 0.f};

    if (s > 0) {
      // wait: all 32 WGs published h[s]
      unsigned int tgt = (unsigned int)s;
      if (tid < 32) {
        while (__hip_atomic_load(&ready[tid * 16], __ATOMIC_RELAXED,
                                 __HIP_MEMORY_SCOPE_AGENT) < tgt)
          __builtin_amdgcn_s_sleep(1);
      }
      __syncthreads();

      // stage h[s] -> LDS: 16 u64 coherent loads
      const unsigned long long* hrd =
          (const unsigned long long*)(hbuf + (size_t)(s & 1) * (BATCH * HH));
      unsigned long long v[16];
#pragma unroll
      for (int i = 0; i < 16; i++)
        v[i] = __hip_atomic_load(hrd + i * 256 + tid, __ATOMIC_RELAXED,
                                 __HIP_MEMORY_SCOPE_AGENT);
      unsigned long long* hw = (unsigned long long*)hs;
#pragma unroll
      for (int i = 0; i < 16; i++) hw[i * 256 + tid] = v[i];
      __syncthreads();

#pragma unroll
      for (int ks = 0; ks < 16; ks++) {
        f16x8 a0 = *(const f16x8*)((char*)hs + (((ks * 4 + aq) * 32) + am) * 16);
        f16x8 a1 = *(const f16x8*)((char*)hs + (((ks * 4 + aq) * 32) + 16 + am) * 16);
        acc0 = __builtin_amdgcn_mfma_f32_16x16x32_f16(a0, bf[ks], acc0, 0, 0, 0);
        acc1 = __builtin_amdgcn_mfma_f32_16x16x32_f16(a1, bf[ks], acc1, 0, 0, 0);
      }
    }

#pragma unroll
    for (int r = 0; r < 4; r++) {
      int b = rbase + r;
      gb[(gate * 32 + b) * 16 + col]      = acc0[r] + gxr0[r];
      gb[(gate * 32 + b + 16) * 16 + col] = acc1[r] + gxr1[r];
    }
    __syncthreads();

    unsigned short* hwr = hbuf + (size_t)((s + 1) & 1) * (BATCH * HH);
    int k = u0 + ul;
    float h0, h1;
    {
      float i_ = sigm(gb[(0 * 32 + b1) * 16 + ul]), f_ = sigm(gb[(1 * 32 + b1) * 16 + ul]);
      float g_ = tanh_(gb[(2 * 32 + b1) * 16 + ul]), o_ = sigm(gb[(3 * 32 + b1) * 16 + ul]);
      cst0 = f_ * cst0 + i_ * g_;
      h0 = o_ * tanh_(cst0);
      out[(size_t)(b1 * SEG + s) * HH + k] = h0;
    }
    {
      int b2 = b1 + 16;
      float i_ = sigm(gb[(0 * 32 + b2) * 16 + ul]), f_ = sigm(gb[(1 * 32 + b2) * 16 + ul]);
      float g_ = tanh_(gb[(2 * 32 + b2) * 16 + ul]), o_ = sigm(gb[(3 * 32 + b2) * 16 + ul]);
      cst1 = f_ * cst1 + i_ * g_;
      h1 = o_ * tanh_(cst1);
      out[(size_t)(b2 * SEG + s) * HH + k] = h1;
    }

    if (s < SEG - 1) {
      // publish h[s+1]; __syncthreads drains vmcnt(0) before the flag goes out
      __hip_atomic_store(hwr + ((k >> 3) * 32 + b1) * 8 + (k & 7),
                         f16_bits((f16)h0), __ATOMIC_RELAXED, __HIP_MEMORY_SCOPE_AGENT);
      __hip_atomic_store(hwr + ((k >> 3) * 32 + (b1 + 16)) * 8 + (k & 7),
                         f16_bits((f16)h1), __ATOMIC_RELAXED, __HIP_MEMORY_SCOPE_AGENT);
      __syncthreads();
      if (tid == 0)
        __hip_atomic_store(&ready[wg * 16], (unsigned int)(s + 1),
                           __ATOMIC_RELAXED, __HIP_MEMORY_SCOPE_AGENT);
    }
  }
}

// ---------------- launch ----------------
extern "C" void kernel_launch(void* const* d_in, const int* in_sizes, int n_in,
                              void* d_out, int out_size, void* d_ws, size_t ws_size,
                              hipStream_t stream) {
  const float* x    = (const float*)d_in[0];
  const float* w_ih = (const float*)d_in[1];
  const float* w_hh = (const float*)d_in[2];
  const float* b_ih = (const float*)d_in[3];
  const float* b_hh = (const float*)d_in[4];
  float* out = (float*)d_out;

  char* ws = (char*)d_ws;
  f16*   fhi   = (f16*)(ws + 0);            // 1664*2144*2 = 7,135,232
  f16*   w16   = (f16*)(ws + 7135232);      // 2048*2144*2 = 8,785,920
  f16*   whh16 = (f16*)(ws + 15921152);     // 2048*512*2 = 2,097,152
  float* gx    = (float*)(ws + 18018304);   // 1664*2048*4 = 13,631,488
  unsigned short* hbuf  = (unsigned short*)(ws + 31649792); // 2*32KB ping-pong
  unsigned int*   ready = (unsigned int*)(ws + 31715328);   // 32 slots x 64B (512 u32)

  // bit-exact replication of np.linspace(1,600,51) + Python round (half-even)
  TV tv;
  double step = 599.0 / 50.0;
  for (int i = 0; i <= 50; i++) {
    double v = (double)i * step + 1.0;
    tv.v[i] = (int)nearbyint(v);
  }
  tv.v[50] = 600;

  unsigned int* gxcnt = ready + 512;        // 32 u32 tile counters

  prep_kernel<<<dim3(MP + CVB), dim3(256), 0, stream>>>(
      x, fhi, tv, (const float4*)w_ih, (const float4*)w_hh,
      (f16x4*)w16, (f16x4*)whh16, ready);

  fused_kernel<<<dim3(32 + WRK), dim3(256), 0, stream>>>(
      fhi, w16, b_ih, b_hh, whh16, gx, hbuf, ready, gxcnt, out);
}

// Round 10
// 264.750 us; speedup vs baseline: 1.2504x; 1.0199x over previous
//
#include <hip/hip_runtime.h>
#include <math.h>

typedef _Float16 f16;
typedef _Float16 f16x8 __attribute__((ext_vector_type(8)));
typedef _Float16 f16x4 __attribute__((ext_vector_type(4)));
typedef float    f32x4 __attribute__((ext_vector_type(4)));

#define BATCH 32
#define TT    600
#define CC    64
#define SEG   50
#define HH    512
#define G4    2048
#define FF    2144   // IN_SIZE = 64 + 2080
#define MM    1600   // BATCH*SEG
#define MP    1664   // padded: 52*32 (s-major) = 26*64 M-tiles
#define NPAIR 2016   // C*(C-1)/2
#define CVB   512    // convert blocks appended to prep grid
#define WRK   208    // gemm worker blocks (each does exactly 2 of the 416 tiles)
#define SLOT16 16384 // u16 elements per h slot (32*512)

struct TV { int v[51]; };

// async global->LDS, 16B per lane. LDS dest must be wave-uniform base + lane*16.
__device__ __forceinline__ void async_copy16(char* lds, const char* g) {
  __builtin_amdgcn_global_load_lds(
      (const __attribute__((address_space(1))) unsigned int*)g,
      (__attribute__((address_space(3))) unsigned int*)lds, 16, 0, 0);
}

__device__ __forceinline__ float sigm(float x) { return 1.f / (1.f + __expf(-x)); }
__device__ __forceinline__ float tanh_(float x) {
  float ax = fabsf(x);
  float e  = __expf(2.f * ax);
  float t  = 1.f - 2.f / (e + 1.f);   // robust for large |x|
  return x < 0.f ? -t : t;
}
__device__ __forceinline__ unsigned short f16_bits(f16 v) {
  union { f16 f; unsigned short u; } c; c.f = v; return c.u;
}
__device__ __forceinline__ unsigned int f32_bits(float v) {
  union { float f; unsigned int u; } c; c.f = v; return c.u;
}

// ---------------- kernel 1: feats (blocks 0..MP-1) + weight convert (blocks MP..) ----
// Plain cached stores; dispatch boundary makes them visible to the fused kernel.
__global__ void prep_kernel(const float* __restrict__ x, f16* __restrict__ fhi, TV tv,
                            const float4* __restrict__ w_ih, const float4* __restrict__ w_hh,
                            f16x4* __restrict__ w16, f16x4* __restrict__ whh16,
                            unsigned int* __restrict__ ready) {
  __shared__ float xs[13 * CC];
  int m   = blockIdx.x;
  int tid = threadIdx.x;

  if (m >= MP) {              // ---- convert role ----
    int cb   = m - MP;
    int gtid = cb * 256 + tid;
    int nth  = CVB * 256;
    for (int i = gtid; i < G4 * FF / 4; i += nth) {
      float4 v = w_ih[i];
      f16x4 o = {(f16)v.x, (f16)v.y, (f16)v.z, (f16)v.w};
      w16[i] = o;
    }
    for (int i = gtid; i < G4 * HH / 4; i += nth) {
      float4 v = w_hh[i];
      f16x4 o = {(f16)v.x, (f16)v.y, (f16)v.z, (f16)v.w};
      whh16[i] = o;
    }
    if (cb == 0)               // zero 32 ready slots (512 u32) + 32 gx tile counters
      for (int i = tid; i < 544; i += 256) ready[i] = 0u;
    return;
  }

  f16* rhi = fhi + (size_t)m * FF;
  if (m >= MM) {              // zero-pad rows 1600..1663 (s = 50,51) for the GEMM M-edge
    unsigned int* a = (unsigned int*)rhi;
    for (int i = tid; i < FF / 2; i += 256) a[i] = 0u;
    return;
  }
  int bb = m & 31, ss = m >> 5;
  int t0 = tv.v[ss] - 1, t1 = tv.v[ss + 1] - 1;
  int len = t1 - t0;          // #intervals in segment (11..12)
  for (int i = tid; i < (len + 1) * CC; i += 256)
    xs[i] = x[(size_t)bb * TT * CC + (size_t)(t0 + (i >> 6)) * CC + (i & 63)];
  __syncthreads();

  if (tid < CC) {             // inc (cols 0..63) and xa (cols 2080..2143)
    float xa  = xs[tid];
    float inc = xs[len * CC + tid] - xa;
    rhi[tid] = (f16)inc;
    rhi[2080 + tid] = (f16)xa;
  }

  int p0 = tid * 8;           // 252 threads x 8 pairs = 2016 upper-tri pairs
  if (p0 < NPAIR) {
    int c = 0, rem = p0;
    while (rem >= 63 - c) { rem -= 63 - c; c++; }
    int d = c + 1 + rem;
    int cs[8], dd[8];
#pragma unroll
    for (int i = 0; i < 8; i++) {
      cs[i] = c; dd[i] = d;
      d++; if (d == 64) { c++; d = c + 1; }
    }
    float acc[8], xc[8], xd[8];
#pragma unroll
    for (int i = 0; i < 8; i++) { acc[i] = 0.f; xc[i] = xs[cs[i]]; xd[i] = xs[dd[i]]; }
    for (int t = 1; t <= len; t++) {
#pragma unroll
      for (int i = 0; i < 8; i++) {      // Levy area: sum x_c*dx_d - x_d*dx_c
        float nc = xs[t * CC + cs[i]], nd = xs[t * CC + dd[i]];
        acc[i] += xc[i] * (nd - xd[i]) - xd[i] * (nc - xc[i]);
        xc[i] = nc; xd[i] = nd;
      }
    }
#pragma unroll
    for (int i = 0; i < 8; i++) {
      int ci = cs[i], di = dd[i];
      float xac = xs[ci], xad = xs[di];
      float incc = xs[len * CC + ci] - xac, incd = xs[len * CC + di] - xad;
      float v = 0.5f * acc[i] - 0.5f * (xac * incd - xad * incc);
      rhi[64 + p0 + i] = (f16)v;
    }
  }
}

// ---------------- kernel 2: fused GEMM + LSTM, regular launch (240 blocks co-resident) ----
// Blocks 0..31: persistent LSTM. h exchange: 50 never-reused 32KB slots; producers
//   sc1-store + barrier-drain + flag; consumers poll flags then stage the slot via
//   async global_load_lds (plain cached read is coherent: address never touched by
//   this XCD pre-flag, L2s invalidated at dispatch start, data at L3 post-drain).
// Blocks 32..239: GEMM workers, 2 tiles each (M-major), sc1 gx stores + tile counter.
__global__ __launch_bounds__(256) void fused_kernel(
    const f16* __restrict__ fhi, const f16* __restrict__ w16,
    const float* __restrict__ bih, const float* __restrict__ bhh,
    const f16* __restrict__ whh16, float* __restrict__ gx,
    unsigned short* __restrict__ hbuf, unsigned int* __restrict__ ready,
    unsigned int* __restrict__ gxcnt, float* __restrict__ out) {
  __shared__ __align__(16) char smem[40960];  // lstm: hs 32K + gbuf 8K ; gemm: A 4K + B 8K
  int tid  = threadIdx.x;
  int lane = tid & 63;

  if (blockIdx.x >= 32) {
    // ================= GEMM worker role =================
    int w  = blockIdx.x - 32;
    int wn = tid >> 6;
    char* ldsA = smem;
    char* ldsB = smem + 4096;
    int rowq = tid >> 2;            // 0..63
    int colq = (tid & 3) * 8;       // halves
    int ldst = tid * 16;
    int quad16 = (lane >> 4) * 16;
    int am = lane & 15;
    unsigned int* gxa = (unsigned int*)gx;

    for (int t = 0; t < 2; t++) {
      int id = w + t * WRK;         // 0..415, M-major: mt = id/16, nt = id%16
      int mt = id >> 4, nt = id & 15;
      int m0 = mt * 64, n0 = nt * 128;

      const f16* pa  = fhi + (size_t)(m0 + rowq) * FF + colq;
      const f16* pb0 = w16 + (size_t)(n0 + rowq) * FF + colq;
      const f16* pb1 = pb0 + (size_t)64 * FF;

      f32x4 zero4 = {0.f, 0.f, 0.f, 0.f};
      f32x4 acc[4][2];
#pragma unroll
      for (int i = 0; i < 4; i++) { acc[i][0] = zero4; acc[i][1] = zero4; }

      for (int kt = 0; kt < FF / 32; kt++) {
        int koff = kt * 32;
        async_copy16(ldsA + ldst,        (const char*)(pa + koff));
        async_copy16(ldsB + ldst,        (const char*)(pb0 + koff));
        async_copy16(ldsB + 4096 + ldst, (const char*)(pb1 + koff));
        __syncthreads();

        f16x8 bfr[2];
#pragma unroll
        for (int ni = 0; ni < 2; ni++)
          bfr[ni] = *(const f16x8*)(ldsB + (wn * 32 + ni * 16 + am) * 64 + quad16);
#pragma unroll
        for (int mi = 0; mi < 4; mi++) {
          f16x8 ah = *(const f16x8*)(ldsA + (mi * 16 + am) * 64 + quad16);
#pragma unroll
          for (int ni = 0; ni < 2; ni++)
            acc[mi][ni] = __builtin_amdgcn_mfma_f32_16x16x32_f16(ah, bfr[ni], acc[mi][ni], 0, 0, 0);
        }
        __syncthreads();
      }

      // epilogue: sc1 stores so lstm blocks (other XCDs) see gx at the coherence point
#pragma unroll
      for (int ni = 0; ni < 2; ni++) {
        int ncol = n0 + wn * 32 + ni * 16 + (lane & 15);
        float bv = bih[ncol] + bhh[ncol];
#pragma unroll
        for (int mi = 0; mi < 4; mi++) {
          int mrow = m0 + mi * 16 + (lane >> 4) * 4;
#pragma unroll
          for (int r = 0; r < 4; r++)
            __hip_atomic_store(gxa + (size_t)(mrow + r) * G4 + ncol,
                               f32_bits(acc[mi][ni][r] + bv),
                               __ATOMIC_RELAXED, __HIP_MEMORY_SCOPE_AGENT);
        }
      }
      __syncthreads();   // drains vmcnt(0): all this block's gx stores acked
      if (tid == 0)
        __hip_atomic_fetch_add(&gxcnt[mt], 1u, __ATOMIC_RELAXED,
                               __HIP_MEMORY_SCOPE_AGENT);
    }
    return;
  }

  // ================= LSTM role (blocks 0..31) =================
  f16* hs = (f16*)smem;                         // 32 KB, layout [k8][b][8] fp16
  float* gb = (float*)(smem + 32768);           // 8 KB gate exchange [gate][b][16]

  int gate = tid >> 6;
  int u0   = blockIdx.x * 16;
  int wg   = blockIdx.x;

  // preload w_hh fragments: B[k][n] = w_hh[n][k], n = gate*512 + u0 + (lane&15)
  f16x8 bf[16];
  {
    const f16* wrow = whh16 + (size_t)(gate * HH + u0 + (lane & 15)) * HH + (lane >> 4) * 8;
#pragma unroll
    for (int ks = 0; ks < 16; ks++) bf[ks] = *(const f16x8*)(wrow + ks * 32);
  }

  int b1 = tid >> 4;
  int ul = tid & 15;
  float cst0 = 0.f, cst1 = 0.f;
  int aq  = (lane >> 4);
  int am  = (lane & 15);
  int col = lane & 15;
  int rbase = (lane >> 4) * 4;

  for (int s = 0; s < SEG; s++) {
    // gate on gx M-tile (s>>1); odd s was confirmed at s-1. The __syncthreads after
    // the poll orders the subsequent plain gx loads (no hoist past a barrier).
    if ((s & 1) == 0) {
      if (tid == 0) {
        while (__hip_atomic_load(&gxcnt[s >> 1], __ATOMIC_RELAXED,
                                 __HIP_MEMORY_SCOPE_AGENT) < 16u)
          __builtin_amdgcn_s_sleep(1);
      }
      __syncthreads();
    }

    // gx prefetch (plain cached loads; post-flag first touch -> fresh from L3)
    float gxr0[4], gxr1[4];
#pragma unroll
    for (int r = 0; r < 4; r++) {
      int b = rbase + r;
      gxr0[r] = gx[(size_t)((s << 5) + b) * G4 + gate * HH + u0 + col];
      gxr1[r] = gx[(size_t)((s << 5) + b + 16) * G4 + gate * HH + u0 + col];
    }

    f32x4 acc0 = {0.f, 0.f, 0.f, 0.f};
    f32x4 acc1 = {0.f, 0.f, 0.f, 0.f};

    if (s > 0) {
      // wait: all 32 WGs published h[s]
      unsigned int tgt = (unsigned int)s;
      if (tid < 32) {
        while (__hip_atomic_load(&ready[tid * 16], __ATOMIC_RELAXED,
                                 __HIP_MEMORY_SCOPE_AGENT) < tgt)
          __builtin_amdgcn_s_sleep(1);
      }
      __syncthreads();

      // stage h[s] slot -> LDS via async DMA: 8 x 16B/thread, all in flight,
      // one drain at the barrier (no VGPR round-trip, no serialized batches)
      const char* hrd = (const char*)(hbuf + (size_t)s * SLOT16);
#pragma unroll
      for (int c = 0; c < 8; c++)
        async_copy16((char*)hs + c * 4096 + tid * 16, hrd + c * 4096 + tid * 16);
      __syncthreads();

#pragma unroll
      for (int ks = 0; ks < 16; ks++) {
        f16x8 a0 = *(const f16x8*)((char*)hs + (((ks * 4 + aq) * 32) + am) * 16);
        f16x8 a1 = *(const f16x8*)((char*)hs + (((ks * 4 + aq) * 32) + 16 + am) * 16);
        acc0 = __builtin_amdgcn_mfma_f32_16x16x32_f16(a0, bf[ks], acc0, 0, 0, 0);
        acc1 = __builtin_amdgcn_mfma_f32_16x16x32_f16(a1, bf[ks], acc1, 0, 0, 0);
      }
    }

#pragma unroll
    for (int r = 0; r < 4; r++) {
      int b = rbase + r;
      gb[(gate * 32 + b) * 16 + col]      = acc0[r] + gxr0[r];
      gb[(gate * 32 + b + 16) * 16 + col] = acc1[r] + gxr1[r];
    }
    __syncthreads();

    unsigned short* hwr = hbuf + (size_t)(s + 1) * SLOT16;
    int k = u0 + ul;
    float h0, h1;
    {
      float i_ = sigm(gb[(0 * 32 + b1) * 16 + ul]), f_ = sigm(gb[(1 * 32 + b1) * 16 + ul]);
      float g_ = tanh_(gb[(2 * 32 + b1) * 16 + ul]), o_ = sigm(gb[(3 * 32 + b1) * 16 + ul]);
      cst0 = f_ * cst0 + i_ * g_;
      h0 = o_ * tanh_(cst0);
      out[(size_t)(b1 * SEG + s) * HH + k] = h0;
    }
    {
      int b2 = b1 + 16;
      float i_ = sigm(gb[(0 * 32 + b2) * 16 + ul]), f_ = sigm(gb[(1 * 32 + b2) * 16 + ul]);
      float g_ = tanh_(gb[(2 * 32 + b2) * 16 + ul]), o_ = sigm(gb[(3 * 32 + b2) * 16 + ul]);
      cst1 = f_ * cst1 + i_ * g_;
      h1 = o_ * tanh_(cst1);
      out[(size_t)(b2 * SEG + s) * HH + k] = h1;
    }

    if (s < SEG - 1) {
      // publish h[s+1] into slot s+1 (sc1, write-through); __syncthreads drains
      // vmcnt(0) so stores are at the coherence point before the flag goes out
      __hip_atomic_store(hwr + ((k >> 3) * 32 + b1) * 8 + (k & 7),
                         f16_bits((f16)h0), __ATOMIC_RELAXED, __HIP_MEMORY_SCOPE_AGENT);
      __hip_atomic_store(hwr + ((k >> 3) * 32 + (b1 + 16)) * 8 + (k & 7),
                         f16_bits((f16)h1), __ATOMIC_RELAXED, __HIP_MEMORY_SCOPE_AGENT);
      __syncthreads();
      if (tid == 0)
        __hip_atomic_store(&ready[wg * 16], (unsigned int)(s + 1),
                           __ATOMIC_RELAXED, __HIP_MEMORY_SCOPE_AGENT);
    }
  }
}

// ---------------- launch ----------------
extern "C" void kernel_launch(void* const* d_in, const int* in_sizes, int n_in,
                              void* d_out, int out_size, void* d_ws, size_t ws_size,
                              hipStream_t stream) {
  const float* x    = (const float*)d_in[0];
  const float* w_ih = (const float*)d_in[1];
  const float* w_hh = (const float*)d_in[2];
  const float* b_ih = (const float*)d_in[3];
  const float* b_hh = (const float*)d_in[4];
  float* out = (float*)d_out;

  char* ws = (char*)d_ws;
  f16*   fhi   = (f16*)(ws + 0);            // 1664*2144*2 = 7,135,232
  f16*   w16   = (f16*)(ws + 7135232);      // 2048*2144*2 = 8,785,920
  f16*   whh16 = (f16*)(ws + 15921152);     // 2048*512*2 = 2,097,152
  float* gx    = (float*)(ws + 18018304);   // 1664*2048*4 = 13,631,488
  unsigned short* hbuf  = (unsigned short*)(ws + 31649792); // 50 slots x 32KB = 1,638,400
  unsigned int*   ready = (unsigned int*)(ws + 33288192);   // 32 slots x 64B (512 u32)

  // bit-exact replication of np.linspace(1,600,51) + Python round (half-even)
  TV tv;
  double step = 599.0 / 50.0;
  for (int i = 0; i <= 50; i++) {
    double v = (double)i * step + 1.0;
    tv.v[i] = (int)nearbyint(v);
  }
  tv.v[50] = 600;

  unsigned int* gxcnt = ready + 512;        // 32 u32 tile counters

  prep_kernel<<<dim3(MP + CVB), dim3(256), 0, stream>>>(
      x, fhi, tv, (const float4*)w_ih, (const float4*)w_hh,
      (f16x4*)w16, (f16x4*)whh16, ready);

  fused_kernel<<<dim3(32 + WRK), dim3(256), 0, stream>>>(
      fhi, w16, b_ih, b_hh, whh16, gx, hbuf, ready, gxcnt, out);
}